// Round 3
// baseline (997.374 us; speedup 1.0000x reference)
//
#include <hip/hip_runtime.h>

typedef __attribute__((ext_vector_type(8))) short short8;   // 8 bf16 = 4 VGPRs (MFMA A/B frag)
typedef __attribute__((ext_vector_type(4))) float f32x4;    // MFMA C/D frag
typedef __attribute__((ext_vector_type(4))) short short4v;

#define DM 768
#define DP 64

__device__ __forceinline__ unsigned short f2bf(float f) {
  unsigned u = __float_as_uint(f);
  u = u + 0x7fffu + ((u >> 16) & 1u);          // RNE
  return (unsigned short)(u >> 16);
}
__device__ __forceinline__ float bf2f(unsigned short s) {
  return __uint_as_float(((unsigned)s) << 16);
}
// mish(v) = v*tanh(softplus(v)) = v*(t^2+2t)/(t^2+2t+2), t=e^v (exact algebra, one exp)
__device__ __forceinline__ float mishf(float v) {
  float t = __expf(fminf(v, 30.0f));
  float num = t * (t + 2.0f);
  return v * (num / (num + 2.0f));
}

// Pre-pack weight [768,N] fp32 into MFMA B-fragment order, bf16:
//   dst[((kt*(N/16) + nt)*64 + lane)*8 + j] = bf16(src[(kt*32 + (lane>>4)*8 + j)*N + nt*16 + (lane&15)])
__global__ void cvt_frag(const float* __restrict__ src, unsigned short* __restrict__ dst,
                         int N, int ntPer) {
  constexpr int MAXC = 192;
  constexpr int TS = MAXC + 8;
  __shared__ unsigned short tile[32 * TS];
  const int kt = blockIdx.x;
  const int nt0 = blockIdx.y * ntPer;
  const int cols = ntPer * 16;
  for (int e = threadIdx.x; e < 32 * cols; e += blockDim.x) {
    int row = e / cols, col = e - row * cols;
    tile[row * TS + col] = f2bf(src[(kt * 32 + row) * N + nt0 * 16 + col]);
  }
  __syncthreads();
  const int NT = N / 16;
  for (int s = threadIdx.x; s < ntPer * 64; s += blockDim.x) {
    int ntl = s >> 6, l = s & 63;
    int m16 = l & 15, quad = l >> 4;
    short8 v;
    #pragma unroll
    for (int j = 0; j < 8; ++j)
      v[j] = (short)tile[(quad * 8 + j) * TS + ntl * 16 + m16];
    *(short8*)(dst + ((size_t)((kt * NT + nt0 + ntl) * 64 + l)) * 8) = v;
  }
}

// LDS plan (76.9 KB -> 2 blocks/CU):
//   smemX 26,624 B : xs0/xs1 (64 x 104-short chunks, double-buffered) ; later sc (64x64 f32)
//   smemH 50,176 B : hsh (64 x 392-short half-h)                      ; later qsh/qsl/ksh/ksl
//   promf 128 B
__global__ __launch_bounds__(1024, 8) void fused_policy(
    const float* __restrict__ x, const float* __restrict__ b1,
    const float* __restrict__ bq, const float* __restrict__ bk,
    const float* __restrict__ Wp, const float* __restrict__ bp,
    const int* __restrict__ idxs, int n_idx,
    const unsigned short* __restrict__ W1f,   // frag-packed [24][48][64][8]
    const unsigned short* __restrict__ Wqf,   // frag-packed [24][4][64][8]
    const unsigned short* __restrict__ Wkf,   // frag-packed [24][4][64][8]
    float* __restrict__ out) {
  constexpr int XS   = 104;   // 96-col x chunk row stride (shorts), 96+8 pad (208 B, 16B-aligned)
  constexpr int HSH  = 392;   // half-h row stride (shorts), 384+8 (784 B, 16B-aligned)
  constexpr int QKS  = 72;    // q/k row stride (shorts), 144 B 16B-aligned

  __shared__ __align__(16) unsigned char smemX[2 * 64 * XS * 2];   // 26,624
  __shared__ __align__(16) unsigned char smemH[64 * HSH * 2];      // 50,176
  __shared__ float promf[32];

  unsigned short* xs0 = (unsigned short*)smemX;
  unsigned short* xs1 = xs0 + 64 * XS;
  float* sc = (float*)smemX;                        // alias: live P3..P4
  unsigned short* hsh = (unsigned short*)smemH;     // live P1-epi..P2 per pass
  unsigned short* qsh = hsh;                        // alias: live after pass loop
  unsigned short* qsl = hsh + 4608;
  unsigned short* ksh = hsh + 9216;
  unsigned short* ksl = hsh + 13824;

  const int b    = blockIdx.x;
  const int tid  = threadIdx.x;
  const int wave = tid >> 6;
  const int lane = tid & 63;
  const int m16  = lane & 15;
  const int quad = lane >> 4;

  const float* xb = x + (size_t)b * (64 * DM);

  // P1 wave role: one row-tile, 96 cols (6 ct) of the current 384-col half
  const int rt = wave & 3;         // row tile 0..3
  const int cg = wave >> 2;        // col group 0..3 (96 cols each)
  // P2 wave role
  const int qk  = wave >> 3;       // 0 = q, 1 = k
  const int w8  = wave & 7;
  const int rt2 = w8 & 3;
  const int ch  = w8 >> 2;         // 32-col half of the 64 outputs

  f32x4 acc2[2];                   // q/k partial sums, persist across both passes
  #pragma unroll
  for (int c2 = 0; c2 < 2; ++c2)
    #pragma unroll
    for (int r = 0; r < 4; ++r) acc2[c2][r] = 0.0f;

  for (int p = 0; p < 2; ++p) {
    // ---------------- P1: h-half = mish(x@W1[:, p*384..] + b1) -----------------
    f32x4 acc[6];
    #pragma unroll
    for (int ct = 0; ct < 6; ++ct)
      #pragma unroll
      for (int r = 0; r < 4; ++r) acc[ct][r] = 0.0f;

    // frag(kt, ct) = wb + kt*48*64*8 + ct*64*8
    const unsigned short* wb = W1f + ((size_t)((p * 24 + cg * 6) * 64) + lane) * 8;

    float4 pv0, pv1;
    {
      int e1 = tid + 1024;
      pv0 = *(const float4*)(xb + (tid / 24) * DM + (tid % 24) * 4);
      if (e1 < 1536) pv1 = *(const float4*)(xb + (e1 / 24) * DM + (e1 % 24) * 4);
    }

    for (int c = 0; c < 8; ++c) {
      unsigned short* xw = (c & 1) ? xs1 : xs0;
      {
        int e1 = tid + 1024;
        short4v s4;
        s4.x = (short)f2bf(pv0.x); s4.y = (short)f2bf(pv0.y);
        s4.z = (short)f2bf(pv0.z); s4.w = (short)f2bf(pv0.w);
        *(short4v*)(xw + (tid / 24) * XS + (tid % 24) * 4) = s4;
        if (e1 < 1536) {
          s4.x = (short)f2bf(pv1.x); s4.y = (short)f2bf(pv1.y);
          s4.z = (short)f2bf(pv1.z); s4.w = (short)f2bf(pv1.w);
          *(short4v*)(xw + (e1 / 24) * XS + (e1 % 24) * 4) = s4;
        }
      }
      __syncthreads();
      if (c < 7) {  // prefetch next chunk; drains behind this chunk's MFMAs
        int kb = (c + 1) * 96;
        int e1 = tid + 1024;
        pv0 = *(const float4*)(xb + (tid / 24) * DM + kb + (tid % 24) * 4);
        if (e1 < 1536) pv1 = *(const float4*)(xb + (e1 / 24) * DM + kb + (e1 % 24) * 4);
      }
      #pragma unroll
      for (int kk = 0; kk < 3; ++kk) {
        const int kt = c * 3 + kk;
        short8 af = *(const short8*)(xw + (rt * 16 + m16) * XS + kk * 32 + quad * 8);
        #pragma unroll
        for (int g = 0; g < 2; ++g) {
          short8 bf[3];
          #pragma unroll
          for (int j = 0; j < 3; ++j)
            bf[j] = *(const short8*)(wb + (size_t)kt * 24576 + (g * 3 + j) * 512);
          #pragma unroll
          for (int j = 0; j < 3; ++j)
            acc[g * 3 + j] = __builtin_amdgcn_mfma_f32_16x16x32_bf16(af, bf[j], acc[g * 3 + j], 0, 0, 0);
        }
      }
      __syncthreads();   // xs buffer reusable (also covers hsh-write vs prior-pass readers)
    }

    // epilogue: bias + mish -> hsh. C/D layout: row=quad*4+r (within tile), col=m16
    #pragma unroll
    for (int ct = 0; ct < 6; ++ct)
      #pragma unroll
      for (int r = 0; r < 4; ++r) {
        int row = rt * 16 + quad * 4 + r;
        int col = cg * 96 + ct * 16 + m16;                  // local to half
        hsh[row * HSH + col] = f2bf(mishf(acc[ct][r] + b1[p * 384 + col]));
      }
    __syncthreads();

    // ---------------- P2 (partial): q/k += h-half @ W{q,k}[p-half] -------------
    {
      const unsigned short* Wf = qk ? Wkf : Wqf;
      const unsigned short* wfb = Wf + ((size_t)((p * 12 * 4 + ch * 2) * 64) + lane) * 8;
      const int arow = (rt2 * 16 + m16) * HSH;
      #pragma unroll
      for (int kt = 0; kt < 12; ++kt) {
        short8 a = *(const short8*)(hsh + arow + kt * 32 + quad * 8);
        #pragma unroll
        for (int c2 = 0; c2 < 2; ++c2) {
          short8 bf = *(const short8*)(wfb + (size_t)(kt * 4 + c2) * 512);
          acc2[c2] = __builtin_amdgcn_mfma_f32_16x16x32_bf16(a, bf, acc2[c2], 0, 0, 0);
        }
      }
    }
    __syncthreads();   // hsh consumed; next pass may overwrite
  }

  // ---------------- q/k epilogue: bias + hi/lo bf16 split into hsh region ------
  {
    const float* bias = qk ? bk : bq;
    unsigned short* oh = qk ? ksh : qsh;
    unsigned short* ol = qk ? ksl : qsl;
    #pragma unroll
    for (int c2 = 0; c2 < 2; ++c2)
      #pragma unroll
      for (int r = 0; r < 4; ++r) {
        int row = rt2 * 16 + quad * 4 + r;
        int col = ch * 32 + c2 * 16 + m16;
        float v = acc2[c2][r] + bias[col];
        unsigned short vh = f2bf(v);
        unsigned short vl = f2bf(v - bf2f(vh));
        oh[row * QKS + col] = vh;
        ol[row * QKS + col] = vl;
      }
  }
  __syncthreads();

  // ---------------- P3: scores = q@k^T * 0.125 (16 tiles / 16 waves) -----------
  {
    const int rt3 = wave >> 2, ctt = wave & 3;
    f32x4 a3;
    #pragma unroll
    for (int r = 0; r < 4; ++r) a3[r] = 0.0f;
    #pragma unroll
    for (int kt = 0; kt < 2; ++kt) {
      const int k0 = kt * 32;
      short8 ah = *(const short8*)(qsh + (rt3 * 16 + m16) * QKS + k0 + quad * 8);
      short8 al = *(const short8*)(qsl + (rt3 * 16 + m16) * QKS + k0 + quad * 8);
      short8 bh = *(const short8*)(ksh + (ctt * 16 + m16) * QKS + k0 + quad * 8);
      short8 bl = *(const short8*)(ksl + (ctt * 16 + m16) * QKS + k0 + quad * 8);
      a3 = __builtin_amdgcn_mfma_f32_16x16x32_bf16(ah, bh, a3, 0, 0, 0);
      a3 = __builtin_amdgcn_mfma_f32_16x16x32_bf16(ah, bl, a3, 0, 0, 0);
      a3 = __builtin_amdgcn_mfma_f32_16x16x32_bf16(al, bh, a3, 0, 0, 0);
    }
    #pragma unroll
    for (int r = 0; r < 4; ++r)
      sc[(rt3 * 16 + quad * 4 + r) * 64 + ctt * 16 + m16] = a3[r] * 0.125f;

    if (wave == 15 && lane < 32) {
      // promf[rr][c] = bp[c] + sum_d k[56+rr][d] * Wp[d][c]
      const int rr = lane >> 2;
      const int c = lane & 3;
      float s = bp[c];
      const int krow = (56 + rr) * QKS;
      #pragma unroll
      for (int d = 0; d < 64; ++d) {
        float kv = bf2f(ksh[krow + d]) + bf2f(ksl[krow + d]);
        s += kv * Wp[d * 4 + c];
      }
      promf[lane] = s;
    }
  }
  __syncthreads();

  // ---------------- P4: gather policy[:, indices] ------------------------------
  float* outb = out + (size_t)b * n_idx;
  for (int i = tid; i < n_idx; i += 1024) {
    int idx = idxs[i];
    float v;
    if (idx < 4096) {
      v = sc[idx];
    } else {
      int f = idx - 4096;        // flat index into promotion (8,24)==(3,64)
      int r = f / 24;
      int j = f - r * 24;
      int jj = j / 3;
      int cc = j - jj * 3;
      v = sc[(48 + r) * 64 + 56 + jj] + promf[jj * 4 + cc] + promf[jj * 4 + 3];
    }
    outb[i] = v;
  }
}

extern "C" void kernel_launch(void* const* d_in, const int* in_sizes, int n_in,
                              void* d_out, int out_size, void* d_ws, size_t ws_size,
                              hipStream_t stream) {
  const float* x  = (const float*)d_in[0];
  const float* W1 = (const float*)d_in[1];
  const float* b1 = (const float*)d_in[2];
  const float* Wq = (const float*)d_in[3];
  const float* bq = (const float*)d_in[4];
  const float* Wk = (const float*)d_in[5];
  const float* bk = (const float*)d_in[6];
  const float* Wp = (const float*)d_in[7];
  const float* bp = (const float*)d_in[8];
  const int* idxs = (const int*)d_in[9];

  const int B = in_sizes[0] / (64 * DM);   // 2048
  const int n_idx = in_sizes[9];           // 1858

  unsigned short* W1f = (unsigned short*)d_ws;        // [24][48][64][8] bf16 frags
  unsigned short* Wqf = W1f + 768 * 768;              // [24][4][64][8]
  unsigned short* Wkf = Wqf + 64 * 768;

  cvt_frag<<<dim3(24, 4), 256, 0, stream>>>(W1, W1f, 768, 12);
  cvt_frag<<<dim3(24, 1), 256, 0, stream>>>(Wq, Wqf, 64, 4);
  cvt_frag<<<dim3(24, 1), 256, 0, stream>>>(Wk, Wkf, 64, 4);

  fused_policy<<<B, 1024, 0, stream>>>(x, b1, bq, bk, Wp, bp, idxs, n_idx,
                                       W1f, Wqf, Wkf, (float*)d_out);
}